// Round 7
// baseline (534.049 us; speedup 1.0000x reference)
//
#include <hip/hip_runtime.h>

// EquivariantProductBasisBlock (MACE symmetric contraction, corr=3) + o3.Linear
// N=10000 nodes, C=128 channels, L=9 (lmax=2), E=5 elements, fp32 throughout.
//
// R7 changes vs R6:
//  - contract: x (x) x (x) x is symmetric -> T3/T2 folded to upper-triangular
//    monomial coeffs (219 vs 828 FMA per node*dd). Triangular Horner with
//    u,v,w ALL fully unrolled (compile-time indices everywhere; body ~500
//    instr/dd at NPT=2 -- inside the proven no-spill window). Table/LDS
//    shrinks to 1248 floats per (e,c). __launch_bounds__(256,4).
//  - table_kernel: computes rect T3/T2 per dd in LDS (verified logic), then
//    symmetrizes+packs: S3[u<=v<=w] = (sum of 6 perms)/rep, rep in {1,2,6};
//    S2[u<=v] = T2[uv]+T2[vu] (u<v). Packed chunks [C2uv, C3 w=v..8] pad4.
//  - sort / linear kernels unchanged (residue shown to be launch overhead).

#define CCH 128
#define LDIM 9
#define NE 5
#define BLK 256
#define CNPT 2               // nodes per thread in contraction
#define DSTR 312             // packed floats per dd
#define GSTR 1248            // packed floats per (e,c) = 4*DSTR
#define U3LDS 8748           // staged U3 slice (729*12 max)

// ---- packed triangular layout (shared between table_kernel & contract) ----
__host__ __device__ constexpr int vlen_c(int v) { return ((10 - v) + 3) & ~3; }
__host__ __device__ constexpr int chunk_off_c(int u, int v) {
  int o = 4; for (int t = u; t < v; ++t) o += vlen_c(t); return o;
}
__host__ __device__ constexpr int ublen_c(int u) {
  int o = 4; for (int t = u; t < 9; ++t) o += vlen_c(t); return o;
}
__host__ __device__ constexpr int uoff_c(int u) {
  int o = 0; for (int t = 0; t < u; ++t) o += ublen_c(t); return o;
}
// u-block: [C1u, pad, pad, pad, chunk(u,u), chunk(u,u+1), ...]
// chunk(u,v): [C2uv, C3[u][v][w] for w=v..8, pad...] (vlen_c(v) floats)

// ------------------------------------------------------------- sort: count
__global__ __launch_bounds__(BLK) void count_kernel(
    const float* __restrict__ attrs, int N,
    int* __restrict__ elem, int* __restrict__ gcnt) {
  int n = blockIdx.x * BLK + threadIdx.x;
  if (n >= N) return;
  const float* a = attrs + n * NE;
  int e = 0;
#pragma unroll
  for (int j = 1; j < NE; ++j)
    if (a[j] > 0.5f) e = j;
  elem[n] = e;
  int lane = threadIdx.x & 63;
#pragma unroll
  for (int k = 0; k < NE; ++k) {
    unsigned long long m = __ballot(e == k);
    if (m) {
      int leader = __ffsll((long long)m) - 1;
      if (lane == leader) atomicAdd(&gcnt[k], __popcll(m));
    }
  }
}

// ------------------------------------------------------------ sort: prefix
__global__ void offs_kernel(const int* __restrict__ gcnt,
                            int* __restrict__ offs, int* __restrict__ cur) {
  if (threadIdx.x == 0) {
    int acc = 0;
    for (int k = 0; k < NE; ++k) { offs[k] = acc; cur[k] = acc; acc += gcnt[k]; }
    offs[NE] = acc;
  }
}

// ----------------------------------------------------------- sort: scatter
__global__ __launch_bounds__(BLK) void scatter_kernel(
    const int* __restrict__ elem, int N,
    int* __restrict__ cur, int* __restrict__ order) {
  int n = blockIdx.x * BLK + threadIdx.x;
  if (n >= N) return;
  int e = elem[n];
  int lane = threadIdx.x & 63;
#pragma unroll
  for (int k = 0; k < NE; ++k) {
    if (e == k) {
      unsigned long long m = __ballot(1);
      int cnt = __popcll(m);
      int leader = __ffsll((long long)m) - 1;
      int base = 0;
      if (lane == leader) base = atomicAdd(&cur[k], cnt);
      base = __shfl(base, leader);
      int rank = __popcll(m & ((1ull << lane) - 1ull));
      order[base + rank] = n;
    }
  }
}

// -------------------- build + symmetrize + pack U(x)w coefficient tables
__global__ __launch_bounds__(BLK) void table_kernel(
    const float* __restrict__ U3_0, const float* __restrict__ U2_0,
    const float* __restrict__ U1_0, const float* __restrict__ U3_1,
    const float* __restrict__ U2_1, const float* __restrict__ U1_1,
    const float* __restrict__ w3_0, const float* __restrict__ w2_0,
    const float* __restrict__ w1_0, const float* __restrict__ w3_1,
    const float* __restrict__ w2_1, const float* __restrict__ w1_1,
    float* __restrict__ table) {
  int b = blockIdx.x;              // e*CCH + c
  int e = b / CCH, c = b % CCH;
  float* Tg = table + (size_t)b * GSTR;
  __shared__ float Us[U3LDS];      // raw U3 slice [729*K3]
  __shared__ float U2s[324];       // raw U2 slice [81*K2]
  __shared__ float R3[729];        // rect T3 for current dd
  __shared__ float R2[81];
  __shared__ float R1l[9];
  __shared__ float P[DSTR];        // packed output staging
  __shared__ float w3l[12], w2l[4];
  const int tid = threadIdx.x;

#pragma unroll 1
  for (int dd = 0; dd < 4; ++dd) {
    __syncthreads();               // guard prev iteration's LDS reads
    const int d = dd - 1;
    const int K3 = (dd == 0) ? 10 : 12;
    const int K2 = (dd == 0) ? 3 : 4;
    // stage raw U slices (coalesced) + weights
    if (dd == 0) {
      for (int i = tid; i < 7290; i += BLK) Us[i] = U3_0[i];
      for (int i = tid; i < 243; i += BLK)  U2s[i] = U2_0[i];
      if (tid < 10) w3l[tid] = w3_0[(e * 10 + tid) * CCH + c];
      else if (tid < 13) w2l[tid - 10] = w2_0[(e * 3 + (tid - 10)) * CCH + c];
      if (tid < 9) R1l[tid] = U1_0[tid] * w1_0[e * CCH + c];
    } else {
      for (int i = tid; i < 8748; i += BLK) Us[i] = U3_1[d * 8748 + i];
      for (int i = tid; i < 324; i += BLK)  U2s[i] = U2_1[d * 324 + i];
      if (tid < 12) w3l[tid] = w3_1[(e * 12 + tid) * CCH + c];
      else if (tid < 16) w2l[tid - 12] = w2_1[(e * 4 + (tid - 12)) * CCH + c];
      if (tid < 9) R1l[tid] = U1_1[d * 9 + tid] * w1_1[e * CCH + c];
    }
    for (int i = tid; i < DSTR; i += BLK) P[i] = 0.f;
    __syncthreads();
    // rect contraction: R3[r] = sum_k Us[r*K3+k]*w3l[k]
    for (int r = tid; r < 729; r += BLK) {
      float acc = 0.f;
      for (int k = 0; k < K3; ++k) acc += Us[r * K3 + k] * w3l[k];
      R3[r] = acc;
    }
    for (int q = tid; q < 81; q += BLK) {
      float acc = 0.f;
      for (int k = 0; k < K2; ++k) acc += U2s[q * K2 + k] * w2l[k];
      R2[q] = acc;
    }
    __syncthreads();
    // symmetrize + pack (54 workers: 45 chunks + 9 C1 slots)
    if (tid < 45) {
      int u = 0, kk = tid;
      while (kk >= 9 - u) { kk -= 9 - u; ++u; }
      int v = u + kk;
      int base = uoff_c(u) + chunk_off_c(u, v);
      P[base] = (u == v) ? R2[u * 9 + u] : (R2[u * 9 + v] + R2[v * 9 + u]);
      for (int w = v; w < 9; ++w) {
        float s = R3[(u * 9 + v) * 9 + w] + R3[(u * 9 + w) * 9 + v] +
                  R3[(v * 9 + u) * 9 + w] + R3[(v * 9 + w) * 9 + u] +
                  R3[(w * 9 + u) * 9 + v] + R3[(w * 9 + v) * 9 + u];
        int rep = 1 + (u == v) + (v == w) + 3 * ((u == v) & (v == w));
        P[base + 1 + (w - v)] = s / (float)rep;
      }
    } else if (tid < 54) {
      int u = tid - 45;
      P[uoff_c(u)] = R1l[u];
    }
    __syncthreads();
    for (int i = tid; i < DSTR; i += BLK) Tg[dd * DSTR + i] = P[i];
  }
}

// --------------------- symmetric contraction (triangular Horner, packed LDS)
__global__ __launch_bounds__(BLK, 4) void contract_kernel(
    const float* __restrict__ feats, const float* __restrict__ table,
    const int* __restrict__ order, const int* __restrict__ offs,
    float* __restrict__ tmp, int NPAD) {
  const int c = blockIdx.y, e = blockIdx.z;
  const int start = offs[e], end = offs[e + 1];
  const int base = start + blockIdx.x * (BLK * CNPT);
  if (base >= end) return;                      // block-uniform early exit

  __shared__ __align__(16) float T[GSTR];
  {
    const float4* src = (const float4*)(table + (size_t)(e * CCH + c) * GSTR);
    float4* dst = (float4*)T;
    for (int i = threadIdx.x; i < GSTR / 4; i += BLK) dst[i] = src[i];
  }
  __syncthreads();

  const int tid = threadIdx.x;
  float x[CNPT][LDIM];
  int pp[CNPT];
  bool valid[CNPT];
#pragma unroll
  for (int i = 0; i < CNPT; ++i) {
    int p = base + i * BLK + tid;
    valid[i] = (p < end);
    int p2 = valid[i] ? p : (end - 1);          // clamp: stay in-bounds
    pp[i] = p;
    int n = order[p2];
    const float* xp = feats + ((size_t)n * CCH + c) * LDIM;
#pragma unroll
    for (int w = 0; w < LDIM; ++w) x[i][w] = xp[w];
  }

#pragma unroll 1
  for (int dd = 0; dd < 4; ++dd) {
    const float* Tdd = T + dd * DSTR;
    float accd[CNPT];
#pragma unroll
    for (int i = 0; i < CNPT; ++i) accd[i] = 0.f;
#pragma unroll
    for (int u = 0; u < 9; ++u) {               // compile-time u
      float G[CNPT];
      float c1 = Tdd[uoff_c(u)];
#pragma unroll
      for (int i = 0; i < CNPT; ++i) G[i] = c1;
#pragma unroll
      for (int v = u; v < 9; ++v) {             // compile-time v
        const int co = uoff_c(u) + chunk_off_c(u, v);
        float cv[12];
#pragma unroll
        for (int q = 0; q < vlen_c(v) / 4; ++q) {
          float4 t = *(const float4*)(Tdd + co + 4 * q);
          cv[4 * q + 0] = t.x; cv[4 * q + 1] = t.y;
          cv[4 * q + 2] = t.z; cv[4 * q + 3] = t.w;
        }
#pragma unroll
        for (int i = 0; i < CNPT; ++i) {
          float H = cv[0];                      // C2uv
#pragma unroll
          for (int w = v; w < 9; ++w)           // compile-time w
            H = fmaf(cv[1 + (w - v)], x[i][w], H);
          G[i] = fmaf(H, x[i][v], G[i]);
        }
      }
#pragma unroll
      for (int i = 0; i < CNPT; ++i) accd[i] = fmaf(G[i], x[i][u], accd[i]);
    }
    float* o = tmp + (size_t)(dd * CCH + c) * NPAD;
#pragma unroll
    for (int i = 0; i < CNPT; ++i)
      if (valid[i]) o[pp[i]] = accd[i];         // consecutive p -> coalesced
  }
}

// ---------------------- o3.Linear + residual (all dd fused, coalesced writes)
#define NB 16                 // nodes per block
__global__ __launch_bounds__(BLK, 4) void linear_kernel(
    const float* __restrict__ tmp, const float* __restrict__ W0,
    const float* __restrict__ W1, const float* __restrict__ sc,
    const int* __restrict__ order, float* __restrict__ out, int N, int NPAD) {
  const int p0 = blockIdx.x * NB;
  const int co = threadIdx.x & (CCH - 1);
  const int h  = threadIdx.x >> 7;              // 0/1: nodes p0+h*8 .. +8
  __shared__ float S[NB][516];                  // 512 + 4 pad

  float acc[4][8];
#pragma unroll
  for (int dd = 0; dd < 4; ++dd)
#pragma unroll
    for (int j = 0; j < 8; ++j) acc[dd][j] = 0.f;

  const int pbase = p0 + h * 8;
#pragma unroll 2
  for (int ci = 0; ci < CCH; ++ci) {
    float w0v = W0[ci * CCH + co];              // coalesced across lanes
    float w1v = W1[ci * CCH + co];
#pragma unroll
    for (int dd = 0; dd < 4; ++dd) {
      const float4* row =
          (const float4*)(tmp + (size_t)(dd * CCH + ci) * NPAD + pbase);
      float4 a0 = row[0], a1 = row[1];          // wave-uniform -> broadcast
      float wv = (dd == 0) ? w0v : w1v;
      acc[dd][0] = fmaf(a0.x, wv, acc[dd][0]);
      acc[dd][1] = fmaf(a0.y, wv, acc[dd][1]);
      acc[dd][2] = fmaf(a0.z, wv, acc[dd][2]);
      acc[dd][3] = fmaf(a0.w, wv, acc[dd][3]);
      acc[dd][4] = fmaf(a1.x, wv, acc[dd][4]);
      acc[dd][5] = fmaf(a1.y, wv, acc[dd][5]);
      acc[dd][6] = fmaf(a1.z, wv, acc[dd][6]);
      acc[dd][7] = fmaf(a1.w, wv, acc[dd][7]);
    }
  }

  const float s = 0.08838834764831843f;         // 1/sqrt(128)
#pragma unroll
  for (int j = 0; j < 8; ++j) {
    int node = h * 8 + j;
    S[node][co]               = acc[0][j] * s;  // stride-1: conflict-free
    S[node][CCH + co * 3 + 0] = acc[1][j] * s;
    S[node][CCH + co * 3 + 1] = acc[2][j] * s;
    S[node][CCH + co * 3 + 2] = acc[3][j] * s;
  }
  __syncthreads();

  // sc + write: full 512-float rows, float4-coalesced (128 lanes x 16B)
  const int f = threadIdx.x & 127;              // float4 index within row
  const int jj = threadIdx.x >> 7;
#pragma unroll 1
  for (int j = jj; j < NB; j += 2) {
    int p = p0 + j;
    if (p < N) {
      int n = order[p];
      float4 sv = ((const float4*)(sc + (size_t)n * 512))[f];
      float4 ov = ((const float4*)&S[j][0])[f];
      ov.x += sv.x; ov.y += sv.y; ov.z += sv.z; ov.w += sv.w;
      ((float4*)(out + (size_t)n * 512))[f] = ov;
    }
  }
}

// -------------------------------------------------------------------- launch
extern "C" void kernel_launch(void* const* d_in, const int* in_sizes, int n_in,
                              void* d_out, int out_size, void* d_ws, size_t ws_size,
                              hipStream_t stream) {
  const float* feats = (const float*)d_in[0];
  const float* attrs = (const float*)d_in[1];
  const float* sc    = (const float*)d_in[2];
  const float* U3_0  = (const float*)d_in[3];
  const float* U2_0  = (const float*)d_in[4];
  const float* U1_0  = (const float*)d_in[5];
  const float* w3_0  = (const float*)d_in[6];
  const float* w2_0  = (const float*)d_in[7];
  const float* w1_0  = (const float*)d_in[8];
  const float* U3_1  = (const float*)d_in[9];
  const float* U2_1  = (const float*)d_in[10];
  const float* U1_1  = (const float*)d_in[11];
  const float* w3_1  = (const float*)d_in[12];
  const float* w2_1  = (const float*)d_in[13];
  const float* w1_1  = (const float*)d_in[14];
  const float* W0    = (const float*)d_in[15];
  const float* W1    = (const float*)d_in[16];

  const int N = in_sizes[0] / (CCH * LDIM);     // 10000
  const int NPAD = ((N + 15) & ~15) + 16;

  // workspace (floats): table[5*128*GSTR] | tmp[4*C][NPAD] | order elem offs cur gcnt
  float* table = (float*)d_ws;
  float* tmp   = table + (size_t)NE * CCH * GSTR;
  int*   order = (int*)(tmp + (size_t)4 * CCH * NPAD);
  int*   elem  = order + N;
  int*   offs  = elem + N;
  int*   cur   = offs + 8;
  int*   gcnt  = cur + 8;
  float* out   = (float*)d_out;

  hipMemsetAsync(gcnt, 0, NE * sizeof(int), stream);

  const int nblk = (N + BLK - 1) / BLK;
  count_kernel<<<dim3(nblk), dim3(BLK), 0, stream>>>(attrs, N, elem, gcnt);
  offs_kernel<<<dim3(1), dim3(64), 0, stream>>>(gcnt, offs, cur);
  scatter_kernel<<<dim3(nblk), dim3(BLK), 0, stream>>>(elem, N, cur, order);

  table_kernel<<<dim3(NE * CCH), dim3(BLK), 0, stream>>>(
      U3_0, U2_0, U1_0, U3_1, U2_1, U1_1,
      w3_0, w2_0, w1_0, w3_1, w2_1, w1_1, table);

  const int chunks = (N + BLK * CNPT - 1) / (BLK * CNPT);
  contract_kernel<<<dim3(chunks, CCH, NE), dim3(BLK), 0, stream>>>(
      feats, table, order, offs, tmp, NPAD);

  linear_kernel<<<dim3((N + NB - 1) / NB), dim3(BLK), 0, stream>>>(
      tmp, W0, W1, sc, order, out, N, NPAD);
}

// Round 8
// 346.892 us; speedup vs baseline: 1.5395x; 1.5395x over previous
//
#include <hip/hip_runtime.h>

// EquivariantProductBasisBlock (MACE symmetric contraction, corr=3) + o3.Linear
// N=10000 nodes, C=128 channels, L=9 (lmax=2), E=5 elements, fp32 throughout.
//
// R8 changes vs R7 (which spilled: 45 fully-unrolled chunks -> 323 MB scratch):
//  - contract: symmetrize ONLY over (v,w): S3[u][v<w]=T3[uvw]+T3[uwv] (exact,
//    no division). u-loop stays uniform -> ROLLED like proven R4 (runtime u,
//    xu select chain, VGPR-56-no-spill skeleton); v,w unrolled compile-time.
//    Per-u record: 56 floats [T1 | T2[9] | tri S3[45] | pad], 14x ds_read_b128.
//    FMA/node*dd 828 -> 504. Body/u-iter ~270 instr (safe window).
//  - table_kernel: same verified rect R3/R2/R1 build, new per-u packing.
//  - sort / linear kernels unchanged.

#define CCH 128
#define LDIM 9
#define NE 5
#define BLK 256
#define NPT 4                // nodes per thread in contraction
#define UBLK 56              // packed floats per (dd,u)
#define DSTR 504             // per dd = 9*UBLK
#define GSTR 2016            // per (e,c) = 4*DSTR
#define U3LDS 8748           // staged U3 slice (729*12 max)

// tri(v,w) offset within u-block: entry (v,w>=v) at tri_off(v) + (w-v)
__host__ __device__ constexpr int tri_off(int v) {
  return 10 + v * 9 - v * (v - 1) / 2;
}

// ------------------------------------------------------------- sort: count
__global__ __launch_bounds__(BLK) void count_kernel(
    const float* __restrict__ attrs, int N,
    int* __restrict__ elem, int* __restrict__ gcnt) {
  int n = blockIdx.x * BLK + threadIdx.x;
  if (n >= N) return;
  const float* a = attrs + n * NE;
  int e = 0;
#pragma unroll
  for (int j = 1; j < NE; ++j)
    if (a[j] > 0.5f) e = j;
  elem[n] = e;
  int lane = threadIdx.x & 63;
#pragma unroll
  for (int k = 0; k < NE; ++k) {
    unsigned long long m = __ballot(e == k);
    if (m) {
      int leader = __ffsll((long long)m) - 1;
      if (lane == leader) atomicAdd(&gcnt[k], __popcll(m));
    }
  }
}

// ------------------------------------------------------------ sort: prefix
__global__ void offs_kernel(const int* __restrict__ gcnt,
                            int* __restrict__ offs, int* __restrict__ cur) {
  if (threadIdx.x == 0) {
    int acc = 0;
    for (int k = 0; k < NE; ++k) { offs[k] = acc; cur[k] = acc; acc += gcnt[k]; }
    offs[NE] = acc;
  }
}

// ----------------------------------------------------------- sort: scatter
__global__ __launch_bounds__(BLK) void scatter_kernel(
    const int* __restrict__ elem, int N,
    int* __restrict__ cur, int* __restrict__ order) {
  int n = blockIdx.x * BLK + threadIdx.x;
  if (n >= N) return;
  int e = elem[n];
  int lane = threadIdx.x & 63;
#pragma unroll
  for (int k = 0; k < NE; ++k) {
    if (e == k) {
      unsigned long long m = __ballot(1);
      int cnt = __popcll(m);
      int leader = __ffsll((long long)m) - 1;
      int base = 0;
      if (lane == leader) base = atomicAdd(&cur[k], cnt);
      base = __shfl(base, leader);
      int rank = __popcll(m & ((1ull << lane) - 1ull));
      order[base + rank] = n;
    }
  }
}

// -------------------- build + (v,w)-symmetrize + pack U(x)w coeff tables
__global__ __launch_bounds__(BLK) void table_kernel(
    const float* __restrict__ U3_0, const float* __restrict__ U2_0,
    const float* __restrict__ U1_0, const float* __restrict__ U3_1,
    const float* __restrict__ U2_1, const float* __restrict__ U1_1,
    const float* __restrict__ w3_0, const float* __restrict__ w2_0,
    const float* __restrict__ w1_0, const float* __restrict__ w3_1,
    const float* __restrict__ w2_1, const float* __restrict__ w1_1,
    float* __restrict__ table) {
  int b = blockIdx.x;              // e*CCH + c
  int e = b / CCH, c = b % CCH;
  float* Tg = table + (size_t)b * GSTR;
  __shared__ float Us[U3LDS];      // raw U3 slice [729*K3]
  __shared__ float U2s[324];       // raw U2 slice [81*K2]
  __shared__ float R3[729];        // rect T3 for current dd
  __shared__ float R2[81];
  __shared__ float R1l[9];
  __shared__ float w3l[12], w2l[4];
  const int tid = threadIdx.x;

#pragma unroll 1
  for (int dd = 0; dd < 4; ++dd) {
    __syncthreads();               // guard prev iteration's LDS reads
    const int d = dd - 1;
    const int K3 = (dd == 0) ? 10 : 12;
    const int K2 = (dd == 0) ? 3 : 4;
    if (dd == 0) {
      for (int i = tid; i < 7290; i += BLK) Us[i] = U3_0[i];
      for (int i = tid; i < 243; i += BLK)  U2s[i] = U2_0[i];
      if (tid < 10) w3l[tid] = w3_0[(e * 10 + tid) * CCH + c];
      else if (tid < 13) w2l[tid - 10] = w2_0[(e * 3 + (tid - 10)) * CCH + c];
      if (tid < 9) R1l[tid] = U1_0[tid] * w1_0[e * CCH + c];
    } else {
      for (int i = tid; i < 8748; i += BLK) Us[i] = U3_1[d * 8748 + i];
      for (int i = tid; i < 324; i += BLK)  U2s[i] = U2_1[d * 324 + i];
      if (tid < 12) w3l[tid] = w3_1[(e * 12 + tid) * CCH + c];
      else if (tid < 16) w2l[tid - 12] = w2_1[(e * 4 + (tid - 12)) * CCH + c];
      if (tid < 9) R1l[tid] = U1_1[d * 9 + tid] * w1_1[e * CCH + c];
    }
    __syncthreads();
    for (int r = tid; r < 729; r += BLK) {
      float acc = 0.f;
      for (int k = 0; k < K3; ++k) acc += Us[r * K3 + k] * w3l[k];
      R3[r] = acc;
    }
    for (int q = tid; q < 81; q += BLK) {
      float acc = 0.f;
      for (int k = 0; k < K2; ++k) acc += U2s[q * K2 + k] * w2l[k];
      R2[q] = acc;
    }
    __syncthreads();
    // pack per-u records: [T1 | T2[0..8] | tri S3 | pad]
    for (int i = tid; i < DSTR; i += BLK) {
      int u = i / UBLK, r = i % UBLK;
      float val = 0.f;
      if (r == 0) val = R1l[u];
      else if (r <= 9) val = R2[u * 9 + (r - 1)];
      else if (r <= 54) {
        int t = r - 10, v = 0;
        while (t >= 9 - v) { t -= 9 - v; ++v; }
        int w = v + t;
        val = (v == w) ? R3[(u * 9 + v) * 9 + v]
                       : R3[(u * 9 + v) * 9 + w] + R3[(u * 9 + w) * 9 + v];
      }
      Tg[dd * DSTR + i] = val;
    }
  }
}

// --------------- symmetric contraction (tri-(v,w) Horner, rolled dd & u)
__global__ __launch_bounds__(BLK, 3) void contract_kernel(
    const float* __restrict__ feats, const float* __restrict__ table,
    const int* __restrict__ order, const int* __restrict__ offs,
    float* __restrict__ tmp, int NPAD) {
  const int c = blockIdx.y, e = blockIdx.z;
  const int start = offs[e], end = offs[e + 1];
  const int base = start + blockIdx.x * (BLK * NPT);
  if (base >= end) return;                      // block-uniform early exit

  __shared__ __align__(16) float T[GSTR];
  {
    const float4* src = (const float4*)(table + (size_t)(e * CCH + c) * GSTR);
    float4* dst = (float4*)T;
    for (int i = threadIdx.x; i < GSTR / 4; i += BLK) dst[i] = src[i];
  }
  __syncthreads();

  const int tid = threadIdx.x;
  float x[NPT][LDIM];
  int pp[NPT];
  bool valid[NPT];
#pragma unroll
  for (int i = 0; i < NPT; ++i) {
    int p = base + i * BLK + tid;
    valid[i] = (p < end);
    int p2 = valid[i] ? p : (end - 1);          // clamp: stay in-bounds
    pp[i] = p;
    int n = order[p2];
    const float* xp = feats + ((size_t)n * CCH + c) * LDIM;
#pragma unroll
    for (int w = 0; w < LDIM; ++w) x[i][w] = xp[w];
  }

#pragma unroll 1
  for (int dd = 0; dd < 4; ++dd) {
    float accd[NPT];
#pragma unroll
    for (int i = 0; i < NPT; ++i) accd[i] = 0.f;
#pragma unroll 1
    for (int u = 0; u < 9; ++u) {
      const float* B = T + dd * DSTR + u * UBLK;   // 16B-aligned record
      float cb[UBLK];
#pragma unroll
      for (int q = 0; q < UBLK / 4; ++q) {
        float4 t = *(const float4*)(B + 4 * q);
        cb[4 * q + 0] = t.x; cb[4 * q + 1] = t.y;
        cb[4 * q + 2] = t.z; cb[4 * q + 3] = t.w;
      }
      // xu[i] = x[i][u] via select chain (runtime u, compile-time structure)
      float xu[NPT];
#pragma unroll
      for (int i = 0; i < NPT; ++i) {
        float t = x[i][0];
#pragma unroll
        for (int k = 1; k < 9; ++k) t = (u == k) ? x[i][k] : t;
        xu[i] = t;
      }
      float inner[NPT];
#pragma unroll
      for (int i = 0; i < NPT; ++i) inner[i] = cb[0];   // T1[u]
#pragma unroll
      for (int v = 0; v < 9; ++v) {             // compile-time v
#pragma unroll
        for (int i = 0; i < NPT; ++i) {
          float Hv = cb[1 + v];                 // T2[u][v]
#pragma unroll
          for (int w = v; w < 9; ++w)           // compile-time w
            Hv = fmaf(cb[tri_off(v) + (w - v)], x[i][w], Hv);
          inner[i] = fmaf(Hv, x[i][v], inner[i]);
        }
      }
#pragma unroll
      for (int i = 0; i < NPT; ++i) accd[i] = fmaf(inner[i], xu[i], accd[i]);
    }
    float* o = tmp + (size_t)(dd * CCH + c) * NPAD;
#pragma unroll
    for (int i = 0; i < NPT; ++i)
      if (valid[i]) o[pp[i]] = accd[i];         // consecutive p -> coalesced
  }
}

// ---------------------- o3.Linear + residual (all dd fused, coalesced writes)
#define NB 16                 // nodes per block
__global__ __launch_bounds__(BLK, 4) void linear_kernel(
    const float* __restrict__ tmp, const float* __restrict__ W0,
    const float* __restrict__ W1, const float* __restrict__ sc,
    const int* __restrict__ order, float* __restrict__ out, int N, int NPAD) {
  const int p0 = blockIdx.x * NB;
  const int co = threadIdx.x & (CCH - 1);
  const int h  = threadIdx.x >> 7;              // 0/1: nodes p0+h*8 .. +8
  __shared__ float S[NB][516];                  // 512 + 4 pad

  float acc[4][8];
#pragma unroll
  for (int dd = 0; dd < 4; ++dd)
#pragma unroll
    for (int j = 0; j < 8; ++j) acc[dd][j] = 0.f;

  const int pbase = p0 + h * 8;
#pragma unroll 2
  for (int ci = 0; ci < CCH; ++ci) {
    float w0v = W0[ci * CCH + co];              // coalesced across lanes
    float w1v = W1[ci * CCH + co];
#pragma unroll
    for (int dd = 0; dd < 4; ++dd) {
      const float4* row =
          (const float4*)(tmp + (size_t)(dd * CCH + ci) * NPAD + pbase);
      float4 a0 = row[0], a1 = row[1];          // wave-uniform -> broadcast
      float wv = (dd == 0) ? w0v : w1v;
      acc[dd][0] = fmaf(a0.x, wv, acc[dd][0]);
      acc[dd][1] = fmaf(a0.y, wv, acc[dd][1]);
      acc[dd][2] = fmaf(a0.z, wv, acc[dd][2]);
      acc[dd][3] = fmaf(a0.w, wv, acc[dd][3]);
      acc[dd][4] = fmaf(a1.x, wv, acc[dd][4]);
      acc[dd][5] = fmaf(a1.y, wv, acc[dd][5]);
      acc[dd][6] = fmaf(a1.z, wv, acc[dd][6]);
      acc[dd][7] = fmaf(a1.w, wv, acc[dd][7]);
    }
  }

  const float s = 0.08838834764831843f;         // 1/sqrt(128)
#pragma unroll
  for (int j = 0; j < 8; ++j) {
    int node = h * 8 + j;
    S[node][co]               = acc[0][j] * s;  // stride-1: conflict-free
    S[node][CCH + co * 3 + 0] = acc[1][j] * s;
    S[node][CCH + co * 3 + 1] = acc[2][j] * s;
    S[node][CCH + co * 3 + 2] = acc[3][j] * s;
  }
  __syncthreads();

  // sc + write: full 512-float rows, float4-coalesced (128 lanes x 16B)
  const int f = threadIdx.x & 127;              // float4 index within row
  const int jj = threadIdx.x >> 7;
#pragma unroll 1
  for (int j = jj; j < NB; j += 2) {
    int p = p0 + j;
    if (p < N) {
      int n = order[p];
      float4 sv = ((const float4*)(sc + (size_t)n * 512))[f];
      float4 ov = ((const float4*)&S[j][0])[f];
      ov.x += sv.x; ov.y += sv.y; ov.z += sv.z; ov.w += sv.w;
      ((float4*)(out + (size_t)n * 512))[f] = ov;
    }
  }
}

// -------------------------------------------------------------------- launch
extern "C" void kernel_launch(void* const* d_in, const int* in_sizes, int n_in,
                              void* d_out, int out_size, void* d_ws, size_t ws_size,
                              hipStream_t stream) {
  const float* feats = (const float*)d_in[0];
  const float* attrs = (const float*)d_in[1];
  const float* sc    = (const float*)d_in[2];
  const float* U3_0  = (const float*)d_in[3];
  const float* U2_0  = (const float*)d_in[4];
  const float* U1_0  = (const float*)d_in[5];
  const float* w3_0  = (const float*)d_in[6];
  const float* w2_0  = (const float*)d_in[7];
  const float* w1_0  = (const float*)d_in[8];
  const float* U3_1  = (const float*)d_in[9];
  const float* U2_1  = (const float*)d_in[10];
  const float* U1_1  = (const float*)d_in[11];
  const float* w3_1  = (const float*)d_in[12];
  const float* w2_1  = (const float*)d_in[13];
  const float* w1_1  = (const float*)d_in[14];
  const float* W0    = (const float*)d_in[15];
  const float* W1    = (const float*)d_in[16];

  const int N = in_sizes[0] / (CCH * LDIM);     // 10000
  const int NPAD = ((N + 15) & ~15) + 16;

  // workspace (floats): table[5*128*GSTR] | tmp[4*C][NPAD] | order elem offs cur gcnt
  float* table = (float*)d_ws;
  float* tmp   = table + (size_t)NE * CCH * GSTR;
  int*   order = (int*)(tmp + (size_t)4 * CCH * NPAD);
  int*   elem  = order + N;
  int*   offs  = elem + N;
  int*   cur   = offs + 8;
  int*   gcnt  = cur + 8;
  float* out   = (float*)d_out;

  hipMemsetAsync(gcnt, 0, NE * sizeof(int), stream);

  const int nblk = (N + BLK - 1) / BLK;
  count_kernel<<<dim3(nblk), dim3(BLK), 0, stream>>>(attrs, N, elem, gcnt);
  offs_kernel<<<dim3(1), dim3(64), 0, stream>>>(gcnt, offs, cur);
  scatter_kernel<<<dim3(nblk), dim3(BLK), 0, stream>>>(elem, N, cur, order);

  table_kernel<<<dim3(NE * CCH), dim3(BLK), 0, stream>>>(
      U3_0, U2_0, U1_0, U3_1, U2_1, U1_1,
      w3_0, w2_0, w1_0, w3_1, w2_1, w1_1, table);

  const int chunks = (N + BLK * NPT - 1) / (BLK * NPT);
  contract_kernel<<<dim3(chunks, CCH, NE), dim3(BLK), 0, stream>>>(
      feats, table, order, offs, tmp, NPAD);

  linear_kernel<<<dim3((N + NB - 1) / NB), dim3(BLK), 0, stream>>>(
      tmp, W0, W1, sc, order, out, N, NPAD);
}

// Round 9
// 310.375 us; speedup vs baseline: 1.7207x; 1.1177x over previous
//
#include <hip/hip_runtime.h>

// EquivariantProductBasisBlock (MACE symmetric contraction, corr=3) + o3.Linear
// N=10000 nodes, C=128 channels, L=9 (lmax=2), E=5 elements, fp32 throughout.
//
// R9 changes vs R8 (contract/table/sort frozen — R8 verified):
//  - linear_kernel was latency-bound (VALUBusy 15%, 10 tiny broadcast global
//    loads per ci-iter, ~220 cyc stall each). Now a proper LDS-tiled GEMM:
//    stage A[4][128][16] (32 KB) coalesced into LDS once, then thread =
//    (node j, co-octet): 4 conflict-free ds_read_b32 + 4 L1-hit W float4 +
//    32 FMA per ci -> VALU-dominant. S-assembly reuses the same LDS buffer.

#define CCH 128
#define LDIM 9
#define NE 5
#define BLK 256
#define NPT 4                // nodes per thread in contraction
#define UBLK 56              // packed floats per (dd,u)
#define DSTR 504             // per dd = 9*UBLK
#define GSTR 2016            // per (e,c) = 4*DSTR
#define U3LDS 8748           // staged U3 slice (729*12 max)

// tri(v,w) offset within u-block: entry (v,w>=v) at tri_off(v) + (w-v)
__host__ __device__ constexpr int tri_off(int v) {
  return 10 + v * 9 - v * (v - 1) / 2;
}

// ------------------------------------------------------------- sort: count
__global__ __launch_bounds__(BLK) void count_kernel(
    const float* __restrict__ attrs, int N,
    int* __restrict__ elem, int* __restrict__ gcnt) {
  int n = blockIdx.x * BLK + threadIdx.x;
  if (n >= N) return;
  const float* a = attrs + n * NE;
  int e = 0;
#pragma unroll
  for (int j = 1; j < NE; ++j)
    if (a[j] > 0.5f) e = j;
  elem[n] = e;
  int lane = threadIdx.x & 63;
#pragma unroll
  for (int k = 0; k < NE; ++k) {
    unsigned long long m = __ballot(e == k);
    if (m) {
      int leader = __ffsll((long long)m) - 1;
      if (lane == leader) atomicAdd(&gcnt[k], __popcll(m));
    }
  }
}

// ------------------------------------------------------------ sort: prefix
__global__ void offs_kernel(const int* __restrict__ gcnt,
                            int* __restrict__ offs, int* __restrict__ cur) {
  if (threadIdx.x == 0) {
    int acc = 0;
    for (int k = 0; k < NE; ++k) { offs[k] = acc; cur[k] = acc; acc += gcnt[k]; }
    offs[NE] = acc;
  }
}

// ----------------------------------------------------------- sort: scatter
__global__ __launch_bounds__(BLK) void scatter_kernel(
    const int* __restrict__ elem, int N,
    int* __restrict__ cur, int* __restrict__ order) {
  int n = blockIdx.x * BLK + threadIdx.x;
  if (n >= N) return;
  int e = elem[n];
  int lane = threadIdx.x & 63;
#pragma unroll
  for (int k = 0; k < NE; ++k) {
    if (e == k) {
      unsigned long long m = __ballot(1);
      int cnt = __popcll(m);
      int leader = __ffsll((long long)m) - 1;
      int base = 0;
      if (lane == leader) base = atomicAdd(&cur[k], cnt);
      base = __shfl(base, leader);
      int rank = __popcll(m & ((1ull << lane) - 1ull));
      order[base + rank] = n;
    }
  }
}

// -------------------- build + (v,w)-symmetrize + pack U(x)w coeff tables
__global__ __launch_bounds__(BLK) void table_kernel(
    const float* __restrict__ U3_0, const float* __restrict__ U2_0,
    const float* __restrict__ U1_0, const float* __restrict__ U3_1,
    const float* __restrict__ U2_1, const float* __restrict__ U1_1,
    const float* __restrict__ w3_0, const float* __restrict__ w2_0,
    const float* __restrict__ w1_0, const float* __restrict__ w3_1,
    const float* __restrict__ w2_1, const float* __restrict__ w1_1,
    float* __restrict__ table) {
  int b = blockIdx.x;              // e*CCH + c
  int e = b / CCH, c = b % CCH;
  float* Tg = table + (size_t)b * GSTR;
  __shared__ float Us[U3LDS];      // raw U3 slice [729*K3]
  __shared__ float U2s[324];       // raw U2 slice [81*K2]
  __shared__ float R3[729];        // rect T3 for current dd
  __shared__ float R2[81];
  __shared__ float R1l[9];
  __shared__ float w3l[12], w2l[4];
  const int tid = threadIdx.x;

#pragma unroll 1
  for (int dd = 0; dd < 4; ++dd) {
    __syncthreads();               // guard prev iteration's LDS reads
    const int d = dd - 1;
    const int K3 = (dd == 0) ? 10 : 12;
    const int K2 = (dd == 0) ? 3 : 4;
    if (dd == 0) {
      for (int i = tid; i < 7290; i += BLK) Us[i] = U3_0[i];
      for (int i = tid; i < 243; i += BLK)  U2s[i] = U2_0[i];
      if (tid < 10) w3l[tid] = w3_0[(e * 10 + tid) * CCH + c];
      else if (tid < 13) w2l[tid - 10] = w2_0[(e * 3 + (tid - 10)) * CCH + c];
      if (tid < 9) R1l[tid] = U1_0[tid] * w1_0[e * CCH + c];
    } else {
      for (int i = tid; i < 8748; i += BLK) Us[i] = U3_1[d * 8748 + i];
      for (int i = tid; i < 324; i += BLK)  U2s[i] = U2_1[d * 324 + i];
      if (tid < 12) w3l[tid] = w3_1[(e * 12 + tid) * CCH + c];
      else if (tid < 16) w2l[tid - 12] = w2_1[(e * 4 + (tid - 12)) * CCH + c];
      if (tid < 9) R1l[tid] = U1_1[d * 9 + tid] * w1_1[e * CCH + c];
    }
    __syncthreads();
    for (int r = tid; r < 729; r += BLK) {
      float acc = 0.f;
      for (int k = 0; k < K3; ++k) acc += Us[r * K3 + k] * w3l[k];
      R3[r] = acc;
    }
    for (int q = tid; q < 81; q += BLK) {
      float acc = 0.f;
      for (int k = 0; k < K2; ++k) acc += U2s[q * K2 + k] * w2l[k];
      R2[q] = acc;
    }
    __syncthreads();
    // pack per-u records: [T1 | T2[0..8] | tri S3 | pad]
    for (int i = tid; i < DSTR; i += BLK) {
      int u = i / UBLK, r = i % UBLK;
      float val = 0.f;
      if (r == 0) val = R1l[u];
      else if (r <= 9) val = R2[u * 9 + (r - 1)];
      else if (r <= 54) {
        int t = r - 10, v = 0;
        while (t >= 9 - v) { t -= 9 - v; ++v; }
        int w = v + t;
        val = (v == w) ? R3[(u * 9 + v) * 9 + v]
                       : R3[(u * 9 + v) * 9 + w] + R3[(u * 9 + w) * 9 + v];
      }
      Tg[dd * DSTR + i] = val;
    }
  }
}

// --------------- symmetric contraction (tri-(v,w) Horner, rolled dd & u)
__global__ __launch_bounds__(BLK, 3) void contract_kernel(
    const float* __restrict__ feats, const float* __restrict__ table,
    const int* __restrict__ order, const int* __restrict__ offs,
    float* __restrict__ tmp, int NPAD) {
  const int c = blockIdx.y, e = blockIdx.z;
  const int start = offs[e], end = offs[e + 1];
  const int base = start + blockIdx.x * (BLK * NPT);
  if (base >= end) return;                      // block-uniform early exit

  __shared__ __align__(16) float T[GSTR];
  {
    const float4* src = (const float4*)(table + (size_t)(e * CCH + c) * GSTR);
    float4* dst = (float4*)T;
    for (int i = threadIdx.x; i < GSTR / 4; i += BLK) dst[i] = src[i];
  }
  __syncthreads();

  const int tid = threadIdx.x;
  float x[NPT][LDIM];
  int pp[NPT];
  bool valid[NPT];
#pragma unroll
  for (int i = 0; i < NPT; ++i) {
    int p = base + i * BLK + tid;
    valid[i] = (p < end);
    int p2 = valid[i] ? p : (end - 1);          // clamp: stay in-bounds
    pp[i] = p;
    int n = order[p2];
    const float* xp = feats + ((size_t)n * CCH + c) * LDIM;
#pragma unroll
    for (int w = 0; w < LDIM; ++w) x[i][w] = xp[w];
  }

#pragma unroll 1
  for (int dd = 0; dd < 4; ++dd) {
    float accd[NPT];
#pragma unroll
    for (int i = 0; i < NPT; ++i) accd[i] = 0.f;
#pragma unroll 1
    for (int u = 0; u < 9; ++u) {
      const float* B = T + dd * DSTR + u * UBLK;   // 16B-aligned record
      float cb[UBLK];
#pragma unroll
      for (int q = 0; q < UBLK / 4; ++q) {
        float4 t = *(const float4*)(B + 4 * q);
        cb[4 * q + 0] = t.x; cb[4 * q + 1] = t.y;
        cb[4 * q + 2] = t.z; cb[4 * q + 3] = t.w;
      }
      // xu[i] = x[i][u] via select chain (runtime u, compile-time structure)
      float xu[NPT];
#pragma unroll
      for (int i = 0; i < NPT; ++i) {
        float t = x[i][0];
#pragma unroll
        for (int k = 1; k < 9; ++k) t = (u == k) ? x[i][k] : t;
        xu[i] = t;
      }
      float inner[NPT];
#pragma unroll
      for (int i = 0; i < NPT; ++i) inner[i] = cb[0];   // T1[u]
#pragma unroll
      for (int v = 0; v < 9; ++v) {             // compile-time v
#pragma unroll
        for (int i = 0; i < NPT; ++i) {
          float Hv = cb[1 + v];                 // T2[u][v]
#pragma unroll
          for (int w = v; w < 9; ++w)           // compile-time w
            Hv = fmaf(cb[tri_off(v) + (w - v)], x[i][w], Hv);
          inner[i] = fmaf(Hv, x[i][v], inner[i]);
        }
      }
#pragma unroll
      for (int i = 0; i < NPT; ++i) accd[i] = fmaf(inner[i], xu[i], accd[i]);
    }
    float* o = tmp + (size_t)(dd * CCH + c) * NPAD;
#pragma unroll
    for (int i = 0; i < NPT; ++i)
      if (valid[i]) o[pp[i]] = accd[i];         // consecutive p -> coalesced
  }
}

// ------------- o3.Linear + residual: LDS-tiled GEMM, coalesced in and out
#define NB 16                 // nodes per block
// LDS union: phase 1-2 use A[4][128][16] (8192 floats); phase 3-4 use
// S[16][516] (8256 floats). 8448 floats = 33 KB.
__global__ __launch_bounds__(BLK, 4) void linear_kernel(
    const float* __restrict__ tmp, const float* __restrict__ W0,
    const float* __restrict__ W1, const float* __restrict__ sc,
    const int* __restrict__ order, float* __restrict__ out, int N, int NPAD) {
  const int p0 = blockIdx.x * NB;
  const int t = threadIdx.x;
  __shared__ __align__(16) float SU[8448];

  // ---- phase 1: stage A[dd][ci][j] = tmp[dd][ci][p0+j], coalesced float4
#pragma unroll
  for (int k = 0; k < 8; ++k) {
    int f = t + k * BLK;               // float4 index 0..2047
    int dd = f >> 9, r = f & 511;
    int ci = r >> 2, q = f & 3;
    float4 v = *(const float4*)(tmp + (size_t)(dd * CCH + ci) * NPAD + p0 + q * 4);
    *(float4*)(SU + dd * 2048 + ci * 16 + q * 4) = v;
  }
  __syncthreads();

  // ---- phase 2: thread = (node j, co-octet o). 32 FMA per ci.
  const int j = t & 15;                // node within tile
  const int o = t >> 4;                // 16 octets of 8 co
  float acc[4][8];
#pragma unroll
  for (int dd = 0; dd < 4; ++dd)
#pragma unroll
    for (int k = 0; k < 8; ++k) acc[dd][k] = 0.f;

  const float* W0p = W0 + o * 8;
  const float* W1p = W1 + o * 8;
#pragma unroll 2
  for (int ci = 0; ci < CCH; ++ci) {
    // A broadcasts: 16 consecutive banks, 4-lane same-address groups -> free
    float a0 = SU[0 * 2048 + ci * 16 + j];
    float a1 = SU[1 * 2048 + ci * 16 + j];
    float a2 = SU[2 * 2048 + ci * 16 + j];
    float a3 = SU[3 * 2048 + ci * 16 + j];
    float4 wa = *(const float4*)(W0p + ci * CCH);
    float4 wb = *(const float4*)(W0p + ci * CCH + 4);
    float4 wc = *(const float4*)(W1p + ci * CCH);
    float4 wd = *(const float4*)(W1p + ci * CCH + 4);
    acc[0][0] = fmaf(a0, wa.x, acc[0][0]);
    acc[0][1] = fmaf(a0, wa.y, acc[0][1]);
    acc[0][2] = fmaf(a0, wa.z, acc[0][2]);
    acc[0][3] = fmaf(a0, wa.w, acc[0][3]);
    acc[0][4] = fmaf(a0, wb.x, acc[0][4]);
    acc[0][5] = fmaf(a0, wb.y, acc[0][5]);
    acc[0][6] = fmaf(a0, wb.z, acc[0][6]);
    acc[0][7] = fmaf(a0, wb.w, acc[0][7]);
    acc[1][0] = fmaf(a1, wc.x, acc[1][0]);
    acc[1][1] = fmaf(a1, wc.y, acc[1][1]);
    acc[1][2] = fmaf(a1, wc.z, acc[1][2]);
    acc[1][3] = fmaf(a1, wc.w, acc[1][3]);
    acc[1][4] = fmaf(a1, wd.x, acc[1][4]);
    acc[1][5] = fmaf(a1, wd.y, acc[1][5]);
    acc[1][6] = fmaf(a1, wd.z, acc[1][6]);
    acc[1][7] = fmaf(a1, wd.w, acc[1][7]);
    acc[2][0] = fmaf(a2, wc.x, acc[2][0]);
    acc[2][1] = fmaf(a2, wc.y, acc[2][1]);
    acc[2][2] = fmaf(a2, wc.z, acc[2][2]);
    acc[2][3] = fmaf(a2, wc.w, acc[2][3]);
    acc[2][4] = fmaf(a2, wd.x, acc[2][4]);
    acc[2][5] = fmaf(a2, wd.y, acc[2][5]);
    acc[2][6] = fmaf(a2, wd.z, acc[2][6]);
    acc[2][7] = fmaf(a2, wd.w, acc[2][7]);
    acc[3][0] = fmaf(a3, wc.x, acc[3][0]);
    acc[3][1] = fmaf(a3, wc.y, acc[3][1]);
    acc[3][2] = fmaf(a3, wc.z, acc[3][2]);
    acc[3][3] = fmaf(a3, wc.w, acc[3][3]);
    acc[3][4] = fmaf(a3, wd.x, acc[3][4]);
    acc[3][5] = fmaf(a3, wd.y, acc[3][5]);
    acc[3][6] = fmaf(a3, wd.z, acc[3][6]);
    acc[3][7] = fmaf(a3, wd.w, acc[3][7]);
  }
  __syncthreads();                     // A dead; SU becomes S[16][516]

  // ---- phase 3: assemble output rows in LDS
  const float s = 0.08838834764831843f;        // 1/sqrt(128)
  float* Sj = SU + j * 516;
#pragma unroll
  for (int k = 0; k < 8; ++k) {
    int co = o * 8 + k;
    Sj[co]               = acc[0][k] * s;
    Sj[CCH + co * 3 + 0] = acc[1][k] * s;
    Sj[CCH + co * 3 + 1] = acc[2][k] * s;
    Sj[CCH + co * 3 + 2] = acc[3][k] * s;
  }
  __syncthreads();

  // ---- phase 4: sc + write, full 512-float rows, float4-coalesced
  const int f = t & 127;               // float4 index within row
  const int jj = t >> 7;
#pragma unroll 1
  for (int jr = jj; jr < NB; jr += 2) {
    int p = p0 + jr;
    if (p < N) {
      int n = order[p];
      float4 sv = ((const float4*)(sc + (size_t)n * 512))[f];
      float4 ov = ((const float4*)(SU + jr * 516))[f];
      ov.x += sv.x; ov.y += sv.y; ov.z += sv.z; ov.w += sv.w;
      ((float4*)(out + (size_t)n * 512))[f] = ov;
    }
  }
}

// -------------------------------------------------------------------- launch
extern "C" void kernel_launch(void* const* d_in, const int* in_sizes, int n_in,
                              void* d_out, int out_size, void* d_ws, size_t ws_size,
                              hipStream_t stream) {
  const float* feats = (const float*)d_in[0];
  const float* attrs = (const float*)d_in[1];
  const float* sc    = (const float*)d_in[2];
  const float* U3_0  = (const float*)d_in[3];
  const float* U2_0  = (const float*)d_in[4];
  const float* U1_0  = (const float*)d_in[5];
  const float* w3_0  = (const float*)d_in[6];
  const float* w2_0  = (const float*)d_in[7];
  const float* w1_0  = (const float*)d_in[8];
  const float* U3_1  = (const float*)d_in[9];
  const float* U2_1  = (const float*)d_in[10];
  const float* U1_1  = (const float*)d_in[11];
  const float* w3_1  = (const float*)d_in[12];
  const float* w2_1  = (const float*)d_in[13];
  const float* w1_1  = (const float*)d_in[14];
  const float* W0    = (const float*)d_in[15];
  const float* W1    = (const float*)d_in[16];

  const int N = in_sizes[0] / (CCH * LDIM);     // 10000
  const int NPAD = ((N + 15) & ~15) + 16;

  // workspace (floats): table[5*128*GSTR] | tmp[4*C][NPAD] | order elem offs cur gcnt
  float* table = (float*)d_ws;
  float* tmp   = table + (size_t)NE * CCH * GSTR;
  int*   order = (int*)(tmp + (size_t)4 * CCH * NPAD);
  int*   elem  = order + N;
  int*   offs  = elem + N;
  int*   cur   = offs + 8;
  int*   gcnt  = cur + 8;
  float* out   = (float*)d_out;

  hipMemsetAsync(gcnt, 0, NE * sizeof(int), stream);

  const int nblk = (N + BLK - 1) / BLK;
  count_kernel<<<dim3(nblk), dim3(BLK), 0, stream>>>(attrs, N, elem, gcnt);
  offs_kernel<<<dim3(1), dim3(64), 0, stream>>>(gcnt, offs, cur);
  scatter_kernel<<<dim3(nblk), dim3(BLK), 0, stream>>>(elem, N, cur, order);

  table_kernel<<<dim3(NE * CCH), dim3(BLK), 0, stream>>>(
      U3_0, U2_0, U1_0, U3_1, U2_1, U1_1,
      w3_0, w2_0, w1_0, w3_1, w2_1, w1_1, table);

  const int chunks = (N + BLK * NPT - 1) / (BLK * NPT);
  contract_kernel<<<dim3(chunks, CCH, NE), dim3(BLK), 0, stream>>>(
      feats, table, order, offs, tmp, NPAD);

  linear_kernel<<<dim3((N + NB - 1) / NB), dim3(BLK), 0, stream>>>(
      tmp, W0, W1, sc, order, out, N, NPAD);
}

// Round 10
// 300.541 us; speedup vs baseline: 1.7770x; 1.0327x over previous
//
#include <hip/hip_runtime.h>

// EquivariantProductBasisBlock (MACE symmetric contraction, corr=3) + o3.Linear
// N=10000 nodes, C=128 channels, L=9 (lmax=2), E=5 elements, fp32 throughout.
//
// R10 changes vs R9 (contract math / linear kernel frozen — both verified):
//  - table_kernel: dd is now blockIdx.y (grid 640x4). The old 4-phase serial
//    dd loop (4x 35KB stage + 8 barriers per block at 2.5 blocks/CU) was the
//    hidden ~40-60us cost. One stage per block, latency hidden by 10 blk/CU.
//  - count+offs fused via last-block ticket (one launch fewer).
//  - contract: grid axes swapped to (c, chunk, e) so real blocks dispatch
//    densely (empty tail chunks no longer interleave).

#define CCH 128
#define LDIM 9
#define NE 5
#define BLK 256
#define NPT 4                // nodes per thread in contraction
#define UBLK 56              // packed floats per (dd,u)
#define DSTR 504             // per dd = 9*UBLK
#define GSTR 2016            // per (e,c) = 4*DSTR
#define U3LDS 8748           // staged U3 slice (729*12 max)

// tri(v,w) offset within u-block: entry (v,w>=v) at tri_off(v) + (w-v)
__host__ __device__ constexpr int tri_off(int v) {
  return 10 + v * 9 - v * (v - 1) / 2;
}

// -------------------------------------------- sort: count + offs (fused)
__global__ __launch_bounds__(BLK) void count_offs_kernel(
    const float* __restrict__ attrs, int N,
    int* __restrict__ elem, int* __restrict__ gcnt,   // gcnt[5], gcnt[5]=done
    int* __restrict__ offs, int* __restrict__ cur) {
  int n = blockIdx.x * BLK + threadIdx.x;
  int e = 0;
  if (n < N) {
    const float* a = attrs + n * NE;
#pragma unroll
    for (int j = 1; j < NE; ++j)
      if (a[j] > 0.5f) e = j;
    elem[n] = e;
  }
  int lane = threadIdx.x & 63;
#pragma unroll
  for (int k = 0; k < NE; ++k) {
    unsigned long long m = __ballot(n < N && e == k);
    if (m) {
      int leader = __ffsll((long long)m) - 1;
      if (lane == leader) atomicAdd(&gcnt[k], __popcll(m));
    }
  }
  __threadfence();
  __syncthreads();
  if (threadIdx.x == 0) {
    int t = atomicAdd(&gcnt[NE], 1);
    if (t == (int)gridDim.x - 1) {            // last block: prefix sum
      int acc = 0;
      for (int k = 0; k < NE; ++k) {
        int ck = atomicAdd(&gcnt[k], 0);      // coherent read
        offs[k] = acc; cur[k] = acc; acc += ck;
      }
      offs[NE] = acc;
    }
  }
}

// ----------------------------------------------------------- sort: scatter
__global__ __launch_bounds__(BLK) void scatter_kernel(
    const int* __restrict__ elem, int N,
    int* __restrict__ cur, int* __restrict__ order) {
  int n = blockIdx.x * BLK + threadIdx.x;
  if (n >= N) return;
  int e = elem[n];
  int lane = threadIdx.x & 63;
#pragma unroll
  for (int k = 0; k < NE; ++k) {
    if (e == k) {
      unsigned long long m = __ballot(1);
      int cnt = __popcll(m);
      int leader = __ffsll((long long)m) - 1;
      int base = 0;
      if (lane == leader) base = atomicAdd(&cur[k], cnt);
      base = __shfl(base, leader);
      int rank = __popcll(m & ((1ull << lane) - 1ull));
      order[base + rank] = n;
    }
  }
}

// ------------- build + (v,w)-symmetrize + pack U(x)w tables (one dd/block)
__global__ __launch_bounds__(BLK) void table_kernel(
    const float* __restrict__ U3_0, const float* __restrict__ U2_0,
    const float* __restrict__ U1_0, const float* __restrict__ U3_1,
    const float* __restrict__ U2_1, const float* __restrict__ U1_1,
    const float* __restrict__ w3_0, const float* __restrict__ w2_0,
    const float* __restrict__ w1_0, const float* __restrict__ w3_1,
    const float* __restrict__ w2_1, const float* __restrict__ w1_1,
    float* __restrict__ table) {
  const int b = blockIdx.x;        // e*CCH + c
  const int dd = blockIdx.y;       // 0..3
  const int e = b / CCH, c = b % CCH;
  float* Tg = table + (size_t)b * GSTR + dd * DSTR;
  __shared__ float Us[U3LDS];      // raw U3 slice [729*K3]
  __shared__ float U2s[324];       // raw U2 slice [81*K2]
  __shared__ float R3[729];        // rect T3
  __shared__ float R2[81];
  __shared__ float R1l[9];
  __shared__ float w3l[12], w2l[4];
  const int tid = threadIdx.x;
  const int d = dd - 1;
  const int K3 = (dd == 0) ? 10 : 12;
  const int K2 = (dd == 0) ? 3 : 4;

  if (dd == 0) {
    for (int i = tid; i < 7290; i += BLK) Us[i] = U3_0[i];
    for (int i = tid; i < 243; i += BLK)  U2s[i] = U2_0[i];
    if (tid < 10) w3l[tid] = w3_0[(e * 10 + tid) * CCH + c];
    else if (tid < 13) w2l[tid - 10] = w2_0[(e * 3 + (tid - 10)) * CCH + c];
    if (tid < 9) R1l[tid] = U1_0[tid] * w1_0[e * CCH + c];
  } else {
    for (int i = tid; i < 8748; i += BLK) Us[i] = U3_1[d * 8748 + i];
    for (int i = tid; i < 324; i += BLK)  U2s[i] = U2_1[d * 324 + i];
    if (tid < 12) w3l[tid] = w3_1[(e * 12 + tid) * CCH + c];
    else if (tid < 16) w2l[tid - 12] = w2_1[(e * 4 + (tid - 12)) * CCH + c];
    if (tid < 9) R1l[tid] = U1_1[d * 9 + tid] * w1_1[e * CCH + c];
  }
  __syncthreads();
  for (int r = tid; r < 729; r += BLK) {
    float acc = 0.f;
    for (int k = 0; k < K3; ++k) acc += Us[r * K3 + k] * w3l[k];
    R3[r] = acc;
  }
  for (int q = tid; q < 81; q += BLK) {
    float acc = 0.f;
    for (int k = 0; k < K2; ++k) acc += U2s[q * K2 + k] * w2l[k];
    R2[q] = acc;
  }
  __syncthreads();
  // pack per-u records: [T1 | T2[0..8] | tri S3 | pad]
  for (int i = tid; i < DSTR; i += BLK) {
    int u = i / UBLK, r = i % UBLK;
    float val = 0.f;
    if (r == 0) val = R1l[u];
    else if (r <= 9) val = R2[u * 9 + (r - 1)];
    else if (r <= 54) {
      int t = r - 10, v = 0;
      while (t >= 9 - v) { t -= 9 - v; ++v; }
      int w = v + t;
      val = (v == w) ? R3[(u * 9 + v) * 9 + v]
                     : R3[(u * 9 + v) * 9 + w] + R3[(u * 9 + w) * 9 + v];
    }
    Tg[i] = val;
  }
}

// --------------- symmetric contraction (tri-(v,w) Horner, rolled dd & u)
__global__ __launch_bounds__(BLK, 3) void contract_kernel(
    const float* __restrict__ feats, const float* __restrict__ table,
    const int* __restrict__ order, const int* __restrict__ offs,
    float* __restrict__ tmp, int NPAD) {
  const int c = blockIdx.x, e = blockIdx.z;     // c fastest -> dense dispatch
  const int start = offs[e], end = offs[e + 1];
  const int base = start + blockIdx.y * (BLK * NPT);
  if (base >= end) return;                      // block-uniform early exit

  __shared__ __align__(16) float T[GSTR];
  {
    const float4* src = (const float4*)(table + (size_t)(e * CCH + c) * GSTR);
    float4* dst = (float4*)T;
    for (int i = threadIdx.x; i < GSTR / 4; i += BLK) dst[i] = src[i];
  }
  __syncthreads();

  const int tid = threadIdx.x;
  float x[NPT][LDIM];
  int pp[NPT];
  bool valid[NPT];
#pragma unroll
  for (int i = 0; i < NPT; ++i) {
    int p = base + i * BLK + tid;
    valid[i] = (p < end);
    int p2 = valid[i] ? p : (end - 1);          // clamp: stay in-bounds
    pp[i] = p;
    int n = order[p2];
    const float* xp = feats + ((size_t)n * CCH + c) * LDIM;
#pragma unroll
    for (int w = 0; w < LDIM; ++w) x[i][w] = xp[w];
  }

#pragma unroll 1
  for (int dd = 0; dd < 4; ++dd) {
    float accd[NPT];
#pragma unroll
    for (int i = 0; i < NPT; ++i) accd[i] = 0.f;
#pragma unroll 1
    for (int u = 0; u < 9; ++u) {
      const float* B = T + dd * DSTR + u * UBLK;   // 16B-aligned record
      float cb[UBLK];
#pragma unroll
      for (int q = 0; q < UBLK / 4; ++q) {
        float4 t = *(const float4*)(B + 4 * q);
        cb[4 * q + 0] = t.x; cb[4 * q + 1] = t.y;
        cb[4 * q + 2] = t.z; cb[4 * q + 3] = t.w;
      }
      // xu[i] = x[i][u] via select chain (runtime u, compile-time structure)
      float xu[NPT];
#pragma unroll
      for (int i = 0; i < NPT; ++i) {
        float t = x[i][0];
#pragma unroll
        for (int k = 1; k < 9; ++k) t = (u == k) ? x[i][k] : t;
        xu[i] = t;
      }
      float inner[NPT];
#pragma unroll
      for (int i = 0; i < NPT; ++i) inner[i] = cb[0];   // T1[u]
#pragma unroll
      for (int v = 0; v < 9; ++v) {             // compile-time v
#pragma unroll
        for (int i = 0; i < NPT; ++i) {
          float Hv = cb[1 + v];                 // T2[u][v]
#pragma unroll
          for (int w = v; w < 9; ++w)           // compile-time w
            Hv = fmaf(cb[tri_off(v) + (w - v)], x[i][w], Hv);
          inner[i] = fmaf(Hv, x[i][v], inner[i]);
        }
      }
#pragma unroll
      for (int i = 0; i < NPT; ++i) accd[i] = fmaf(inner[i], xu[i], accd[i]);
    }
    float* o = tmp + (size_t)(dd * CCH + c) * NPAD;
#pragma unroll
    for (int i = 0; i < NPT; ++i)
      if (valid[i]) o[pp[i]] = accd[i];         // consecutive p -> coalesced
  }
}

// ------------- o3.Linear + residual: LDS-tiled GEMM, coalesced in and out
#define NB 16                 // nodes per block
__global__ __launch_bounds__(BLK, 4) void linear_kernel(
    const float* __restrict__ tmp, const float* __restrict__ W0,
    const float* __restrict__ W1, const float* __restrict__ sc,
    const int* __restrict__ order, float* __restrict__ out, int N, int NPAD) {
  const int p0 = blockIdx.x * NB;
  const int t = threadIdx.x;
  __shared__ __align__(16) float SU[8448];

  // ---- phase 1: stage A[dd][ci][j] = tmp[dd][ci][p0+j], coalesced float4
#pragma unroll
  for (int k = 0; k < 8; ++k) {
    int f = t + k * BLK;               // float4 index 0..2047
    int dd = f >> 9, r = f & 511;
    int ci = r >> 2, q = f & 3;
    float4 v = *(const float4*)(tmp + (size_t)(dd * CCH + ci) * NPAD + p0 + q * 4);
    *(float4*)(SU + dd * 2048 + ci * 16 + q * 4) = v;
  }
  __syncthreads();

  // ---- phase 2: thread = (node j, co-octet o). 32 FMA per ci.
  const int j = t & 15;                // node within tile
  const int o = t >> 4;                // 16 octets of 8 co
  float acc[4][8];
#pragma unroll
  for (int dd = 0; dd < 4; ++dd)
#pragma unroll
    for (int k = 0; k < 8; ++k) acc[dd][k] = 0.f;

  const float* W0p = W0 + o * 8;
  const float* W1p = W1 + o * 8;
#pragma unroll 2
  for (int ci = 0; ci < CCH; ++ci) {
    float a0 = SU[0 * 2048 + ci * 16 + j];
    float a1 = SU[1 * 2048 + ci * 16 + j];
    float a2 = SU[2 * 2048 + ci * 16 + j];
    float a3 = SU[3 * 2048 + ci * 16 + j];
    float4 wa = *(const float4*)(W0p + ci * CCH);
    float4 wb = *(const float4*)(W0p + ci * CCH + 4);
    float4 wc = *(const float4*)(W1p + ci * CCH);
    float4 wd = *(const float4*)(W1p + ci * CCH + 4);
    acc[0][0] = fmaf(a0, wa.x, acc[0][0]);
    acc[0][1] = fmaf(a0, wa.y, acc[0][1]);
    acc[0][2] = fmaf(a0, wa.z, acc[0][2]);
    acc[0][3] = fmaf(a0, wa.w, acc[0][3]);
    acc[0][4] = fmaf(a0, wb.x, acc[0][4]);
    acc[0][5] = fmaf(a0, wb.y, acc[0][5]);
    acc[0][6] = fmaf(a0, wb.z, acc[0][6]);
    acc[0][7] = fmaf(a0, wb.w, acc[0][7]);
    acc[1][0] = fmaf(a1, wc.x, acc[1][0]);
    acc[1][1] = fmaf(a1, wc.y, acc[1][1]);
    acc[1][2] = fmaf(a1, wc.z, acc[1][2]);
    acc[1][3] = fmaf(a1, wc.w, acc[1][3]);
    acc[1][4] = fmaf(a1, wd.x, acc[1][4]);
    acc[1][5] = fmaf(a1, wd.y, acc[1][5]);
    acc[1][6] = fmaf(a1, wd.z, acc[1][6]);
    acc[1][7] = fmaf(a1, wd.w, acc[1][7]);
    acc[2][0] = fmaf(a2, wc.x, acc[2][0]);
    acc[2][1] = fmaf(a2, wc.y, acc[2][1]);
    acc[2][2] = fmaf(a2, wc.z, acc[2][2]);
    acc[2][3] = fmaf(a2, wc.w, acc[2][3]);
    acc[2][4] = fmaf(a2, wd.x, acc[2][4]);
    acc[2][5] = fmaf(a2, wd.y, acc[2][5]);
    acc[2][6] = fmaf(a2, wd.z, acc[2][6]);
    acc[2][7] = fmaf(a2, wd.w, acc[2][7]);
    acc[3][0] = fmaf(a3, wc.x, acc[3][0]);
    acc[3][1] = fmaf(a3, wc.y, acc[3][1]);
    acc[3][2] = fmaf(a3, wc.z, acc[3][2]);
    acc[3][3] = fmaf(a3, wc.w, acc[3][3]);
    acc[3][4] = fmaf(a3, wd.x, acc[3][4]);
    acc[3][5] = fmaf(a3, wd.y, acc[3][5]);
    acc[3][6] = fmaf(a3, wd.z, acc[3][6]);
    acc[3][7] = fmaf(a3, wd.w, acc[3][7]);
  }
  __syncthreads();                     // A dead; SU becomes S[16][516]

  // ---- phase 3: assemble output rows in LDS
  const float s = 0.08838834764831843f;        // 1/sqrt(128)
  float* Sj = SU + j * 516;
#pragma unroll
  for (int k = 0; k < 8; ++k) {
    int co = o * 8 + k;
    Sj[co]               = acc[0][k] * s;
    Sj[CCH + co * 3 + 0] = acc[1][k] * s;
    Sj[CCH + co * 3 + 1] = acc[2][k] * s;
    Sj[CCH + co * 3 + 2] = acc[3][k] * s;
  }
  __syncthreads();

  // ---- phase 4: sc + write, full 512-float rows, float4-coalesced
  const int f = t & 127;               // float4 index within row
  const int jj = t >> 7;
#pragma unroll 1
  for (int jr = jj; jr < NB; jr += 2) {
    int p = p0 + jr;
    if (p < N) {
      int n = order[p];
      float4 sv = ((const float4*)(sc + (size_t)n * 512))[f];
      float4 ov = ((const float4*)(SU + jr * 516))[f];
      ov.x += sv.x; ov.y += sv.y; ov.z += sv.z; ov.w += sv.w;
      ((float4*)(out + (size_t)n * 512))[f] = ov;
    }
  }
}

// -------------------------------------------------------------------- launch
extern "C" void kernel_launch(void* const* d_in, const int* in_sizes, int n_in,
                              void* d_out, int out_size, void* d_ws, size_t ws_size,
                              hipStream_t stream) {
  const float* feats = (const float*)d_in[0];
  const float* attrs = (const float*)d_in[1];
  const float* sc    = (const float*)d_in[2];
  const float* U3_0  = (const float*)d_in[3];
  const float* U2_0  = (const float*)d_in[4];
  const float* U1_0  = (const float*)d_in[5];
  const float* w3_0  = (const float*)d_in[6];
  const float* w2_0  = (const float*)d_in[7];
  const float* w1_0  = (const float*)d_in[8];
  const float* U3_1  = (const float*)d_in[9];
  const float* U2_1  = (const float*)d_in[10];
  const float* U1_1  = (const float*)d_in[11];
  const float* w3_1  = (const float*)d_in[12];
  const float* w2_1  = (const float*)d_in[13];
  const float* w1_1  = (const float*)d_in[14];
  const float* W0    = (const float*)d_in[15];
  const float* W1    = (const float*)d_in[16];

  const int N = in_sizes[0] / (CCH * LDIM);     // 10000
  const int NPAD = ((N + 15) & ~15) + 16;

  // ws (floats): table[5*128*GSTR] | tmp[4*C][NPAD] | order elem offs(8) cur(8) gcnt(8)
  float* table = (float*)d_ws;
  float* tmp   = table + (size_t)NE * CCH * GSTR;
  int*   order = (int*)(tmp + (size_t)4 * CCH * NPAD);
  int*   elem  = order + N;
  int*   offs  = elem + N;
  int*   cur   = offs + 8;
  int*   gcnt  = cur + 8;                       // gcnt[0..4], gcnt[5]=done
  float* out   = (float*)d_out;

  hipMemsetAsync(gcnt, 0, 8 * sizeof(int), stream);

  const int nblk = (N + BLK - 1) / BLK;
  count_offs_kernel<<<dim3(nblk), dim3(BLK), 0, stream>>>(
      attrs, N, elem, gcnt, offs, cur);
  scatter_kernel<<<dim3(nblk), dim3(BLK), 0, stream>>>(elem, N, cur, order);

  table_kernel<<<dim3(NE * CCH, 4), dim3(BLK), 0, stream>>>(
      U3_0, U2_0, U1_0, U3_1, U2_1, U1_1,
      w3_0, w2_0, w1_0, w3_1, w2_1, w1_1, table);

  const int chunks = (N + BLK * NPT - 1) / (BLK * NPT);
  contract_kernel<<<dim3(CCH, chunks, NE), dim3(BLK), 0, stream>>>(
      feats, table, order, offs, tmp, NPAD);

  linear_kernel<<<dim3((N + NB - 1) / NB), dim3(BLK), 0, stream>>>(
      tmp, W0, W1, sc, order, out, N, NPAD);
}

// Round 11
// 290.013 us; speedup vs baseline: 1.8415x; 1.0363x over previous
//
#include <hip/hip_runtime.h>

// EquivariantProductBasisBlock (MACE symmetric contraction, corr=3) + o3.Linear
// N=10000 nodes, C=128 channels, L=9 (lmax=2), E=5 elements, fp32 throughout.
//
// R11 changes vs R10 (table/linear/sort frozen — all at traffic/issue bounds):
//  - contract: the xu select chain (8 cndmask x 9u x 4dd = 288 VALU/node,
//    12.7% of ops, recomputed per dd) is replaced by an LDS read: block's x
//    staged to XS[1024][9] (36 KB, stride-9 -> conflict-free, gcd(9,32)=1);
//    xu = 1 ds_read_b32 per (dd,u,i). LDS pipe stays under VALU (191 vs 440
//    cyc per u-iter). LDS 45 KB -> 3 blocks/CU, >= measured 2.4 avg.

#define CCH 128
#define LDIM 9
#define NE 5
#define BLK 256
#define NPT 4                // nodes per thread in contraction
#define UBLK 56              // packed floats per (dd,u)
#define DSTR 504             // per dd = 9*UBLK
#define GSTR 2016            // per (e,c) = 4*DSTR
#define U3LDS 8748           // staged U3 slice (729*12 max)

// tri(v,w) offset within u-block: entry (v,w>=v) at tri_off(v) + (w-v)
__host__ __device__ constexpr int tri_off(int v) {
  return 10 + v * 9 - v * (v - 1) / 2;
}

// -------------------------------------------- sort: count + offs (fused)
__global__ __launch_bounds__(BLK) void count_offs_kernel(
    const float* __restrict__ attrs, int N,
    int* __restrict__ elem, int* __restrict__ gcnt,   // gcnt[5], gcnt[5]=done
    int* __restrict__ offs, int* __restrict__ cur) {
  int n = blockIdx.x * BLK + threadIdx.x;
  int e = 0;
  if (n < N) {
    const float* a = attrs + n * NE;
#pragma unroll
    for (int j = 1; j < NE; ++j)
      if (a[j] > 0.5f) e = j;
    elem[n] = e;
  }
  int lane = threadIdx.x & 63;
#pragma unroll
  for (int k = 0; k < NE; ++k) {
    unsigned long long m = __ballot(n < N && e == k);
    if (m) {
      int leader = __ffsll((long long)m) - 1;
      if (lane == leader) atomicAdd(&gcnt[k], __popcll(m));
    }
  }
  __threadfence();
  __syncthreads();
  if (threadIdx.x == 0) {
    int t = atomicAdd(&gcnt[NE], 1);
    if (t == (int)gridDim.x - 1) {            // last block: prefix sum
      int acc = 0;
      for (int k = 0; k < NE; ++k) {
        int ck = atomicAdd(&gcnt[k], 0);      // coherent read
        offs[k] = acc; cur[k] = acc; acc += ck;
      }
      offs[NE] = acc;
    }
  }
}

// ----------------------------------------------------------- sort: scatter
__global__ __launch_bounds__(BLK) void scatter_kernel(
    const int* __restrict__ elem, int N,
    int* __restrict__ cur, int* __restrict__ order) {
  int n = blockIdx.x * BLK + threadIdx.x;
  if (n >= N) return;
  int e = elem[n];
  int lane = threadIdx.x & 63;
#pragma unroll
  for (int k = 0; k < NE; ++k) {
    if (e == k) {
      unsigned long long m = __ballot(1);
      int cnt = __popcll(m);
      int leader = __ffsll((long long)m) - 1;
      int base = 0;
      if (lane == leader) base = atomicAdd(&cur[k], cnt);
      base = __shfl(base, leader);
      int rank = __popcll(m & ((1ull << lane) - 1ull));
      order[base + rank] = n;
    }
  }
}

// ------------- build + (v,w)-symmetrize + pack U(x)w tables (one dd/block)
__global__ __launch_bounds__(BLK) void table_kernel(
    const float* __restrict__ U3_0, const float* __restrict__ U2_0,
    const float* __restrict__ U1_0, const float* __restrict__ U3_1,
    const float* __restrict__ U2_1, const float* __restrict__ U1_1,
    const float* __restrict__ w3_0, const float* __restrict__ w2_0,
    const float* __restrict__ w1_0, const float* __restrict__ w3_1,
    const float* __restrict__ w2_1, const float* __restrict__ w1_1,
    float* __restrict__ table) {
  const int b = blockIdx.x;        // e*CCH + c
  const int dd = blockIdx.y;       // 0..3
  const int e = b / CCH, c = b % CCH;
  float* Tg = table + (size_t)b * GSTR + dd * DSTR;
  __shared__ float Us[U3LDS];      // raw U3 slice [729*K3]
  __shared__ float U2s[324];       // raw U2 slice [81*K2]
  __shared__ float R3[729];        // rect T3
  __shared__ float R2[81];
  __shared__ float R1l[9];
  __shared__ float w3l[12], w2l[4];
  const int tid = threadIdx.x;
  const int d = dd - 1;
  const int K3 = (dd == 0) ? 10 : 12;
  const int K2 = (dd == 0) ? 3 : 4;

  if (dd == 0) {
    for (int i = tid; i < 7290; i += BLK) Us[i] = U3_0[i];
    for (int i = tid; i < 243; i += BLK)  U2s[i] = U2_0[i];
    if (tid < 10) w3l[tid] = w3_0[(e * 10 + tid) * CCH + c];
    else if (tid < 13) w2l[tid - 10] = w2_0[(e * 3 + (tid - 10)) * CCH + c];
    if (tid < 9) R1l[tid] = U1_0[tid] * w1_0[e * CCH + c];
  } else {
    for (int i = tid; i < 8748; i += BLK) Us[i] = U3_1[d * 8748 + i];
    for (int i = tid; i < 324; i += BLK)  U2s[i] = U2_1[d * 324 + i];
    if (tid < 12) w3l[tid] = w3_1[(e * 12 + tid) * CCH + c];
    else if (tid < 16) w2l[tid - 12] = w2_1[(e * 4 + (tid - 12)) * CCH + c];
    if (tid < 9) R1l[tid] = U1_1[d * 9 + tid] * w1_1[e * CCH + c];
  }
  __syncthreads();
  for (int r = tid; r < 729; r += BLK) {
    float acc = 0.f;
    for (int k = 0; k < K3; ++k) acc += Us[r * K3 + k] * w3l[k];
    R3[r] = acc;
  }
  for (int q = tid; q < 81; q += BLK) {
    float acc = 0.f;
    for (int k = 0; k < K2; ++k) acc += U2s[q * K2 + k] * w2l[k];
    R2[q] = acc;
  }
  __syncthreads();
  // pack per-u records: [T1 | T2[0..8] | tri S3 | pad]
  for (int i = tid; i < DSTR; i += BLK) {
    int u = i / UBLK, r = i % UBLK;
    float val = 0.f;
    if (r == 0) val = R1l[u];
    else if (r <= 9) val = R2[u * 9 + (r - 1)];
    else if (r <= 54) {
      int t = r - 10, v = 0;
      while (t >= 9 - v) { t -= 9 - v; ++v; }
      int w = v + t;
      val = (v == w) ? R3[(u * 9 + v) * 9 + v]
                     : R3[(u * 9 + v) * 9 + w] + R3[(u * 9 + w) * 9 + v];
    }
    Tg[i] = val;
  }
}

// --------------- symmetric contraction (tri-(v,w) Horner, rolled dd & u)
__global__ __launch_bounds__(BLK, 3) void contract_kernel(
    const float* __restrict__ feats, const float* __restrict__ table,
    const int* __restrict__ order, const int* __restrict__ offs,
    float* __restrict__ tmp, int NPAD) {
  const int c = blockIdx.x, e = blockIdx.z;     // c fastest -> dense dispatch
  const int start = offs[e], end = offs[e + 1];
  const int base = start + blockIdx.y * (BLK * NPT);
  if (base >= end) return;                      // block-uniform early exit

  __shared__ __align__(16) float T[GSTR];
  __shared__ float XS[BLK * NPT * LDIM];        // x staged for xu ds_read
  {
    const float4* src = (const float4*)(table + (size_t)(e * CCH + c) * GSTR);
    float4* dst = (float4*)T;
    for (int i = threadIdx.x; i < GSTR / 4; i += BLK) dst[i] = src[i];
  }

  const int tid = threadIdx.x;
  float x[NPT][LDIM];
  int pp[NPT];
  bool valid[NPT];
#pragma unroll
  for (int i = 0; i < NPT; ++i) {
    int p = base + i * BLK + tid;
    valid[i] = (p < end);
    int p2 = valid[i] ? p : (end - 1);          // clamp: stay in-bounds
    pp[i] = p;
    int n = order[p2];
    const float* xp = feats + ((size_t)n * CCH + c) * LDIM;
#pragma unroll
    for (int w = 0; w < LDIM; ++w) x[i][w] = xp[w];
#pragma unroll
    for (int w = 0; w < LDIM; ++w)
      XS[(i * BLK + tid) * LDIM + w] = x[i][w]; // stride-9: conflict-free
  }
  __syncthreads();

#pragma unroll 1
  for (int dd = 0; dd < 4; ++dd) {
    float accd[NPT];
#pragma unroll
    for (int i = 0; i < NPT; ++i) accd[i] = 0.f;
#pragma unroll 1
    for (int u = 0; u < 9; ++u) {
      const float* B = T + dd * DSTR + u * UBLK;   // 16B-aligned record
      float cb[UBLK];
#pragma unroll
      for (int q = 0; q < UBLK / 4; ++q) {
        float4 t = *(const float4*)(B + 4 * q);
        cb[4 * q + 0] = t.x; cb[4 * q + 1] = t.y;
        cb[4 * q + 2] = t.z; cb[4 * q + 3] = t.w;
      }
      // xu via LDS read (replaces 8-deep cndmask chain; stride-9 banks)
      float xu[NPT];
#pragma unroll
      for (int i = 0; i < NPT; ++i)
        xu[i] = XS[(i * BLK + tid) * LDIM + u];
      float inner[NPT];
#pragma unroll
      for (int i = 0; i < NPT; ++i) inner[i] = cb[0];   // T1[u]
#pragma unroll
      for (int v = 0; v < 9; ++v) {             // compile-time v
#pragma unroll
        for (int i = 0; i < NPT; ++i) {
          float Hv = cb[1 + v];                 // T2[u][v]
#pragma unroll
          for (int w = v; w < 9; ++w)           // compile-time w
            Hv = fmaf(cb[tri_off(v) + (w - v)], x[i][w], Hv);
          inner[i] = fmaf(Hv, x[i][v], inner[i]);
        }
      }
#pragma unroll
      for (int i = 0; i < NPT; ++i) accd[i] = fmaf(inner[i], xu[i], accd[i]);
    }
    float* o = tmp + (size_t)(dd * CCH + c) * NPAD;
#pragma unroll
    for (int i = 0; i < NPT; ++i)
      if (valid[i]) o[pp[i]] = accd[i];         // consecutive p -> coalesced
  }
}

// ------------- o3.Linear + residual: LDS-tiled GEMM, coalesced in and out
#define NB 16                 // nodes per block
__global__ __launch_bounds__(BLK, 4) void linear_kernel(
    const float* __restrict__ tmp, const float* __restrict__ W0,
    const float* __restrict__ W1, const float* __restrict__ sc,
    const int* __restrict__ order, float* __restrict__ out, int N, int NPAD) {
  const int p0 = blockIdx.x * NB;
  const int t = threadIdx.x;
  __shared__ __align__(16) float SU[8448];

  // ---- phase 1: stage A[dd][ci][j] = tmp[dd][ci][p0+j], coalesced float4
#pragma unroll
  for (int k = 0; k < 8; ++k) {
    int f = t + k * BLK;               // float4 index 0..2047
    int dd = f >> 9, r = f & 511;
    int ci = r >> 2, q = f & 3;
    float4 v = *(const float4*)(tmp + (size_t)(dd * CCH + ci) * NPAD + p0 + q * 4);
    *(float4*)(SU + dd * 2048 + ci * 16 + q * 4) = v;
  }
  __syncthreads();

  // ---- phase 2: thread = (node j, co-octet o). 32 FMA per ci.
  const int j = t & 15;                // node within tile
  const int o = t >> 4;                // 16 octets of 8 co
  float acc[4][8];
#pragma unroll
  for (int dd = 0; dd < 4; ++dd)
#pragma unroll
    for (int k = 0; k < 8; ++k) acc[dd][k] = 0.f;

  const float* W0p = W0 + o * 8;
  const float* W1p = W1 + o * 8;
#pragma unroll 2
  for (int ci = 0; ci < CCH; ++ci) {
    float a0 = SU[0 * 2048 + ci * 16 + j];
    float a1 = SU[1 * 2048 + ci * 16 + j];
    float a2 = SU[2 * 2048 + ci * 16 + j];
    float a3 = SU[3 * 2048 + ci * 16 + j];
    float4 wa = *(const float4*)(W0p + ci * CCH);
    float4 wb = *(const float4*)(W0p + ci * CCH + 4);
    float4 wc = *(const float4*)(W1p + ci * CCH);
    float4 wd = *(const float4*)(W1p + ci * CCH + 4);
    acc[0][0] = fmaf(a0, wa.x, acc[0][0]);
    acc[0][1] = fmaf(a0, wa.y, acc[0][1]);
    acc[0][2] = fmaf(a0, wa.z, acc[0][2]);
    acc[0][3] = fmaf(a0, wa.w, acc[0][3]);
    acc[0][4] = fmaf(a0, wb.x, acc[0][4]);
    acc[0][5] = fmaf(a0, wb.y, acc[0][5]);
    acc[0][6] = fmaf(a0, wb.z, acc[0][6]);
    acc[0][7] = fmaf(a0, wb.w, acc[0][7]);
    acc[1][0] = fmaf(a1, wc.x, acc[1][0]);
    acc[1][1] = fmaf(a1, wc.y, acc[1][1]);
    acc[1][2] = fmaf(a1, wc.z, acc[1][2]);
    acc[1][3] = fmaf(a1, wc.w, acc[1][3]);
    acc[1][4] = fmaf(a1, wd.x, acc[1][4]);
    acc[1][5] = fmaf(a1, wd.y, acc[1][5]);
    acc[1][6] = fmaf(a1, wd.z, acc[1][6]);
    acc[1][7] = fmaf(a1, wd.w, acc[1][7]);
    acc[2][0] = fmaf(a2, wc.x, acc[2][0]);
    acc[2][1] = fmaf(a2, wc.y, acc[2][1]);
    acc[2][2] = fmaf(a2, wc.z, acc[2][2]);
    acc[2][3] = fmaf(a2, wc.w, acc[2][3]);
    acc[2][4] = fmaf(a2, wd.x, acc[2][4]);
    acc[2][5] = fmaf(a2, wd.y, acc[2][5]);
    acc[2][6] = fmaf(a2, wd.z, acc[2][6]);
    acc[2][7] = fmaf(a2, wd.w, acc[2][7]);
    acc[3][0] = fmaf(a3, wc.x, acc[3][0]);
    acc[3][1] = fmaf(a3, wc.y, acc[3][1]);
    acc[3][2] = fmaf(a3, wc.z, acc[3][2]);
    acc[3][3] = fmaf(a3, wc.w, acc[3][3]);
    acc[3][4] = fmaf(a3, wd.x, acc[3][4]);
    acc[3][5] = fmaf(a3, wd.y, acc[3][5]);
    acc[3][6] = fmaf(a3, wd.z, acc[3][6]);
    acc[3][7] = fmaf(a3, wd.w, acc[3][7]);
  }
  __syncthreads();                     // A dead; SU becomes S[16][516]

  // ---- phase 3: assemble output rows in LDS
  const float s = 0.08838834764831843f;        // 1/sqrt(128)
  float* Sj = SU + j * 516;
#pragma unroll
  for (int k = 0; k < 8; ++k) {
    int co = o * 8 + k;
    Sj[co]               = acc[0][k] * s;
    Sj[CCH + co * 3 + 0] = acc[1][k] * s;
    Sj[CCH + co * 3 + 1] = acc[2][k] * s;
    Sj[CCH + co * 3 + 2] = acc[3][k] * s;
  }
  __syncthreads();

  // ---- phase 4: sc + write, full 512-float rows, float4-coalesced
  const int f = t & 127;               // float4 index within row
  const int jj = t >> 7;
#pragma unroll 1
  for (int jr = jj; jr < NB; jr += 2) {
    int p = p0 + jr;
    if (p < N) {
      int n = order[p];
      float4 sv = ((const float4*)(sc + (size_t)n * 512))[f];
      float4 ov = ((const float4*)(SU + jr * 516))[f];
      ov.x += sv.x; ov.y += sv.y; ov.z += sv.z; ov.w += sv.w;
      ((float4*)(out + (size_t)n * 512))[f] = ov;
    }
  }
}

// -------------------------------------------------------------------- launch
extern "C" void kernel_launch(void* const* d_in, const int* in_sizes, int n_in,
                              void* d_out, int out_size, void* d_ws, size_t ws_size,
                              hipStream_t stream) {
  const float* feats = (const float*)d_in[0];
  const float* attrs = (const float*)d_in[1];
  const float* sc    = (const float*)d_in[2];
  const float* U3_0  = (const float*)d_in[3];
  const float* U2_0  = (const float*)d_in[4];
  const float* U1_0  = (const float*)d_in[5];
  const float* w3_0  = (const float*)d_in[6];
  const float* w2_0  = (const float*)d_in[7];
  const float* w1_0  = (const float*)d_in[8];
  const float* U3_1  = (const float*)d_in[9];
  const float* U2_1  = (const float*)d_in[10];
  const float* U1_1  = (const float*)d_in[11];
  const float* w3_1  = (const float*)d_in[12];
  const float* w2_1  = (const float*)d_in[13];
  const float* w1_1  = (const float*)d_in[14];
  const float* W0    = (const float*)d_in[15];
  const float* W1    = (const float*)d_in[16];

  const int N = in_sizes[0] / (CCH * LDIM);     // 10000
  const int NPAD = ((N + 15) & ~15) + 16;

  // ws (floats): table[5*128*GSTR] | tmp[4*C][NPAD] | order elem offs(8) cur(8) gcnt(8)
  float* table = (float*)d_ws;
  float* tmp   = table + (size_t)NE * CCH * GSTR;
  int*   order = (int*)(tmp + (size_t)4 * CCH * NPAD);
  int*   elem  = order + N;
  int*   offs  = elem + N;
  int*   cur   = offs + 8;
  int*   gcnt  = cur + 8;                       // gcnt[0..4], gcnt[5]=done
  float* out   = (float*)d_out;

  hipMemsetAsync(gcnt, 0, 8 * sizeof(int), stream);

  const int nblk = (N + BLK - 1) / BLK;
  count_offs_kernel<<<dim3(nblk), dim3(BLK), 0, stream>>>(
      attrs, N, elem, gcnt, offs, cur);
  scatter_kernel<<<dim3(nblk), dim3(BLK), 0, stream>>>(elem, N, cur, order);

  table_kernel<<<dim3(NE * CCH, 4), dim3(BLK), 0, stream>>>(
      U3_0, U2_0, U1_0, U3_1, U2_1, U1_1,
      w3_0, w2_0, w1_0, w3_1, w2_1, w1_1, table);

  const int chunks = (N + BLK * NPT - 1) / (BLK * NPT);
  contract_kernel<<<dim3(CCH, chunks, NE), dim3(BLK), 0, stream>>>(
      feats, table, order, offs, tmp, NPAD);

  linear_kernel<<<dim3((N + NB - 1) / NB), dim3(BLK), 0, stream>>>(
      tmp, W0, W1, sc, order, out, N, NPAD);
}